// Round 1
// baseline (325.664 us; speedup 1.0000x reference)
//
#include <hip/hip_runtime.h>

typedef unsigned short u16;
typedef __bf16 bf16x8 __attribute__((ext_vector_type(8)));
typedef float f32x4 __attribute__((ext_vector_type(4)));

// fp32 -> bf16 round-to-nearest-even (finite values; no NaN path needed here)
__device__ __forceinline__ u16 f2bf(float f) {
  unsigned int u = __float_as_uint(f);
  return (u16)((u + 0x7fffu + ((u >> 16) & 1u)) >> 16);
}

// ---------------------------------------------------------------------------
// Restructure: mean-over-perms commutes with the linear layer, so fold the
// averaging coefficients C_i[g,j] = count_s(perm_s[j]==g)/12 into W:
//   Wtil_i[d, g*512+f] = sum_j C_i[g,j] * W_i[d, j*512+f]
//   out[b, i*1024+d]   = sum_{g,f} bf16(x)[b, g*512+f] * Wtil_i[d, g*512+f] + b_i[d]
// => ONE uniform GEMM 2048 x 7168 x 4096 (A = bf16(x), B = Wtil, both built
// once per call). Eliminates the 73.4 MB Xbar intermediate (write + re-read)
// that made the old prep ~190 us.
// ---------------------------------------------------------------------------

// ---------------------------------------------------------------------------
// Kernel 1: prep (one dispatch).
//   blocks [0,1792):     build Wtil (7168 x 4096 bf16, row-major, K contig),
//                        4 rows per block, one scale per block (4 | 1024).
//   blocks [1792,2048):  cast x fp32 -> bf16 (2048 x 4096), grid-stride.
// ---------------------------------------------------------------------------
__global__ __launch_bounds__(256) void k_prep(
    const float* __restrict__ x,
    const int* p0, const int* p1, const int* p2, const int* p3,
    const int* p4, const int* p5, const int* p6,
    const float* W0, const float* W1, const float* W2, const float* W3,
    const float* W4, const float* W5, const float* W6,
    u16* __restrict__ Xb16, u16* __restrict__ Wtil) {
  __shared__ float sC[64];                 // C_i[g][j], g=0..7, j=0..7
  const int bid = blockIdx.x;
  const int t = threadIdx.x;
  if (bid < 1792) {
    const int r0 = bid << 2;               // global output row (n) base
    const int i = r0 >> 10;                // scale index 0..6 (uniform/block)
    const int scale = 8 - i;
    const int K = scale << 9;              // scale*512
    const int d0 = r0 - (i << 10);
    if (t < 64) {
      const int g = t >> 3, j = t & 7;
      float v = 0.f;
      if (j < scale) {
        const int* p = (i == 0) ? p0 : (i == 1) ? p1 : (i == 2) ? p2 :
                       (i == 3) ? p3 : (i == 4) ? p4 : (i == 5) ? p5 : p6;
        int cnt = 0;
        for (int s = 0; s < 12; ++s) cnt += (p[s * scale + j] == g) ? 1 : 0;
        v = (float)cnt * (1.0f / 12.0f);
      }
      sC[t] = v;
    }
    __syncthreads();
    const float* Wi = (i == 0) ? W0 : (i == 1) ? W1 : (i == 2) ? W2 :
                      (i == 3) ? W3 : (i == 4) ? W4 : (i == 5) ? W5 : W6;
    const int u = t & 63;                  // f-octet: f = u*8 .. u*8+7
    const int gq = t >> 6;                 // wave -> g pair {2gq, 2gq+1}
    u16* dst = Wtil + ((size_t)r0 << 12);  // r0 * 4096
    for (int r = 0; r < 4; ++r) {
      const float* wrow = Wi + (size_t)(d0 + r) * K;
      float a0[8], a1[8];
#pragma unroll
      for (int e = 0; e < 8; ++e) { a0[e] = 0.f; a1[e] = 0.f; }
      for (int j = 0; j < scale; ++j) {    // static reg indices inside (rule #20)
        const float* wp = wrow + j * 512 + (u << 3);
        const float4 wa = *reinterpret_cast<const float4*>(wp);
        const float4 wb = *reinterpret_cast<const float4*>(wp + 4);
        const float c0 = sC[(gq << 4) + j];        // C[2gq][j]
        const float c1 = sC[(gq << 4) + 8 + j];    // C[2gq+1][j]
        a0[0] += c0 * wa.x; a0[1] += c0 * wa.y; a0[2] += c0 * wa.z; a0[3] += c0 * wa.w;
        a0[4] += c0 * wb.x; a0[5] += c0 * wb.y; a0[6] += c0 * wb.z; a0[7] += c0 * wb.w;
        a1[0] += c1 * wa.x; a1[1] += c1 * wa.y; a1[2] += c1 * wa.z; a1[3] += c1 * wa.w;
        a1[4] += c1 * wb.x; a1[5] += c1 * wb.y; a1[6] += c1 * wb.z; a1[7] += c1 * wb.w;
      }
      uint4 o0, o1;
      o0.x = (unsigned)f2bf(a0[0]) | ((unsigned)f2bf(a0[1]) << 16);
      o0.y = (unsigned)f2bf(a0[2]) | ((unsigned)f2bf(a0[3]) << 16);
      o0.z = (unsigned)f2bf(a0[4]) | ((unsigned)f2bf(a0[5]) << 16);
      o0.w = (unsigned)f2bf(a0[6]) | ((unsigned)f2bf(a0[7]) << 16);
      o1.x = (unsigned)f2bf(a1[0]) | ((unsigned)f2bf(a1[1]) << 16);
      o1.y = (unsigned)f2bf(a1[2]) | ((unsigned)f2bf(a1[3]) << 16);
      o1.z = (unsigned)f2bf(a1[4]) | ((unsigned)f2bf(a1[5]) << 16);
      o1.w = (unsigned)f2bf(a1[6]) | ((unsigned)f2bf(a1[7]) << 16);
      u16* drow = dst + ((size_t)r << 12) + (gq << 10) + (u << 3);
      *reinterpret_cast<uint4*>(drow) = o0;        // g = 2gq
      *reinterpret_cast<uint4*>(drow + 512) = o1;  // g = 2gq+1
    }
  } else {
    // x cast: 2048*4096 fp32 -> bf16; 65536 threads x 16 iters x 8 elems
    const int tid0 = ((bid - 1792) << 8) | t;
    const float4* X4 = reinterpret_cast<const float4*>(x);
    uint4* O = reinterpret_cast<uint4*>(Xb16);
#pragma unroll 4
    for (int it = 0; it < 16; ++it) {
      const int e = tid0 + (it << 16);
      const float4 a = X4[(size_t)e * 2];
      const float4 c = X4[(size_t)e * 2 + 1];
      uint4 o;
      o.x = (unsigned)f2bf(a.x) | ((unsigned)f2bf(a.y) << 16);
      o.y = (unsigned)f2bf(a.z) | ((unsigned)f2bf(a.w) << 16);
      o.z = (unsigned)f2bf(c.x) | ((unsigned)f2bf(c.y) << 16);
      o.w = (unsigned)f2bf(c.z) | ((unsigned)f2bf(c.w) << 16);
      O[e] = o;
    }
  }
}

// ---------------------------------------------------------------------------
// Kernel 2: bf16 MFMA GEMM 2048 x 7168 x 4096 (structure identical to the
// proven 92us multi-scale kernel: 128x128 tile, BK=64, dbuf LDS 2x32KB,
// counted vmcnt(8) so current tile's loads stay in flight across the barrier,
// swizzled LDS slot=(chunk+row)&7 -> verified 0 bank conflicts).
// XCD swizzle: bid&7 = XCD; within an XCD, 16 consecutive blocks share one
// 128-row B panel (1 MB, L2-resident); A panels served by L3.
// ---------------------------------------------------------------------------
__device__ __forceinline__ void gl_lds16(const u16* g, u16* l) {
  __builtin_amdgcn_global_load_lds(
      (const __attribute__((address_space(1))) void*)g,
      (__attribute__((address_space(3))) void*)l, 16, 0, 0);
}

#define WAIT_VM8 0x0F78   // vmcnt=8, expcnt=7(nowait), lgkmcnt=15(nowait)
#define WAIT_VM0 0x0F70   // vmcnt=0, expcnt=7, lgkmcnt=15

__global__ __launch_bounds__(256) void k_gemm(
    const u16* __restrict__ A, const u16* __restrict__ Bm,
    const float* b0, const float* b1, const float* b2, const float* b3,
    const float* b4, const float* b5, const float* b6,
    float* __restrict__ out) {
  __shared__ u16 lds[2 * 16384];      // buf b: A at b*16384, B at b*16384+8192
  const int bid = blockIdx.x;         // 896 = 8 XCD * 16 m * 7 n
  const int xcd = bid & 7;
  const int sid = bid >> 3;           // 0..111
  const int m0 = (sid & 15) * 128;            // 16 m-tiles
  const int n0 = (xcd * 7 + (sid >> 4)) * 128; // 56 n-tiles, 7 per XCD

  const int tid = threadIdx.x;
  const int lane = tid & 63;
  const int wave = tid >> 6;
  const int quad = lane >> 4;
  const int l15 = lane & 15;
  const int waveM = (wave >> 1) * 64;
  const int waveN = (wave & 1) * 64;

  // Staging: tile = 128 rows x 128 B = 1024 chunks of 16 B; 4 chunks/thread
  // per matrix. Swizzle: chunk for slot sslot of row srow is (sslot-srow)&7.
  const int srow = tid >> 3;          // 0..31
  const int sslot = tid & 7;
  const int gch = (sslot - srow) & 7;
  const u16* pA0 = A + (size_t)(m0 + srow) * 4096 + gch * 8;
  const u16* pB0 = Bm + (size_t)(n0 + srow) * 4096 + gch * 8;
  const size_t strideR = (size_t)32 * 4096;
  u16* lA0 = lds + tid * 8;
  u16* lB0 = lds + 8192 + tid * 8;

  // LDS read offsets (u16 units, buffer 0): row*64 + (((tt*4+quad)+row)&7)*8
  int offA[2][4], offB[2][4];
#pragma unroll
  for (int tt = 0; tt < 2; ++tt) {
#pragma unroll
    for (int q = 0; q < 4; ++q) {
      int rowA = waveM + q * 16 + l15;
      offA[tt][q] = rowA * 64 + (((tt * 4 + quad) + rowA) & 7) * 8;
      int rowB = waveN + q * 16 + l15;
      offB[tt][q] = 8192 + rowB * 64 + (((tt * 4 + quad) + rowB) & 7) * 8;
    }
  }

  f32x4 acc[4][4];
#pragma unroll
  for (int q = 0; q < 4; ++q)
#pragma unroll
    for (int c = 0; c < 4; ++c) {
      f32x4 z = {0.f, 0.f, 0.f, 0.f};
      acc[q][c] = z;
    }

  // Prologue: tile 0 -> buffer 0
#pragma unroll
  for (int j = 0; j < 4; ++j) {
    gl_lds16(pA0 + j * strideR, lA0 + j * 2048);
    gl_lds16(pB0 + j * strideR, lB0 + j * 2048);
  }

  for (int kt = 0; kt < 63; ++kt) {   // niter = 64
    // Issue next tile into the other buffer (stays in flight past barrier)
    const size_t ko = (size_t)(kt + 1) * 64;
    const int nb = ((kt + 1) & 1) << 14;
#pragma unroll
    for (int j = 0; j < 4; ++j) {
      gl_lds16(pA0 + j * strideR + ko, lA0 + nb + j * 2048);
      gl_lds16(pB0 + j * strideR + ko, lB0 + nb + j * 2048);
    }
    __builtin_amdgcn_s_waitcnt(WAIT_VM8);   // previous tile's 8 loads done
    __builtin_amdgcn_s_barrier();
    const int boff = (kt & 1) << 14;
#pragma unroll
    for (int tt = 0; tt < 2; ++tt) {
      bf16x8 av[4], bv[4];
#pragma unroll
      for (int q = 0; q < 4; ++q) av[q] = *reinterpret_cast<const bf16x8*>(lds + boff + offA[tt][q]);
#pragma unroll
      for (int c = 0; c < 4; ++c) bv[c] = *reinterpret_cast<const bf16x8*>(lds + boff + offB[tt][c]);
#pragma unroll
      for (int q = 0; q < 4; ++q)
#pragma unroll
        for (int c = 0; c < 4; ++c)
          acc[q][c] = __builtin_amdgcn_mfma_f32_16x16x32_bf16(av[q], bv[c], acc[q][c], 0, 0, 0);
    }
    __builtin_amdgcn_s_barrier();   // all waves done reading buf before reuse
  }

  // Final tile (buffer 1)
  __builtin_amdgcn_s_waitcnt(WAIT_VM0);
  __builtin_amdgcn_s_barrier();
  {
    const int boff = 1 << 14;
#pragma unroll
    for (int tt = 0; tt < 2; ++tt) {
      bf16x8 av[4], bv[4];
#pragma unroll
      for (int q = 0; q < 4; ++q) av[q] = *reinterpret_cast<const bf16x8*>(lds + boff + offA[tt][q]);
#pragma unroll
      for (int c = 0; c < 4; ++c) bv[c] = *reinterpret_cast<const bf16x8*>(lds + boff + offB[tt][c]);
#pragma unroll
      for (int q = 0; q < 4; ++q)
#pragma unroll
        for (int c = 0; c < 4; ++c)
          acc[q][c] = __builtin_amdgcn_mfma_f32_16x16x32_bf16(av[q], bv[c], acc[q][c], 0, 0, 0);
    }
  }

  // Epilogue: C/D layout row = quad*4 + reg, col = lane&15; n-panel lies in
  // exactly one scale (128 | 1024) -> uniform bias pointer per block.
  const int isc = n0 >> 10;
  const float* bi = (isc == 0) ? b0 : (isc == 1) ? b1 : (isc == 2) ? b2 :
                    (isc == 3) ? b3 : (isc == 4) ? b4 : (isc == 5) ? b5 : b6;
#pragma unroll
  for (int c = 0; c < 4; ++c) {
    const int ncol = n0 + waveN + c * 16 + l15;
    const float bias = bi[ncol & 1023];
#pragma unroll
    for (int q = 0; q < 4; ++q) {
      const int mbase = m0 + waveM + q * 16 + quad * 4;
#pragma unroll
      for (int reg = 0; reg < 4; ++reg)
        out[(size_t)(mbase + reg) * 7168 + ncol] = acc[q][c][reg] + bias;
    }
  }
}

// ---------------------------------------------------------------------------
extern "C" void kernel_launch(void* const* d_in, const int* in_sizes, int n_in,
                              void* d_out, int out_size, void* d_ws, size_t ws_size,
                              hipStream_t stream) {
  const float* input = (const float*)d_in[0];
  const int* perms[7];
  const float* W[7];
  const float* bias[7];
  for (int i = 0; i < 7; ++i) {
    perms[i] = (const int*)d_in[1 + 3 * i];
    W[i]     = (const float*)d_in[2 + 3 * i];
    bias[i]  = (const float*)d_in[3 + 3 * i];
  }
  char* ws = (char*)d_ws;
  u16* Xb16 = (u16*)ws;                                // 2048*4096 bf16 = 16.8 MB
  u16* Wtil = (u16*)(ws + (size_t)2048 * 4096 * 2);    // 7168*4096 bf16 = 58.7 MB

  k_prep<<<2048, 256, 0, stream>>>(input,
                                   perms[0], perms[1], perms[2], perms[3],
                                   perms[4], perms[5], perms[6],
                                   W[0], W[1], W[2], W[3], W[4], W[5], W[6],
                                   Xb16, Wtil);
  k_gemm<<<896, 256, 0, stream>>>(Xb16, Wtil,
                                  bias[0], bias[1], bias[2], bias[3],
                                  bias[4], bias[5], bias[6],
                                  (float*)d_out);
}

// Round 2
// 303.438 us; speedup vs baseline: 1.0732x; 1.0732x over previous
//
#include <hip/hip_runtime.h>

typedef unsigned short u16;
typedef __bf16 bf16x8 __attribute__((ext_vector_type(8)));
typedef float f32x4 __attribute__((ext_vector_type(4)));

// fp32 -> bf16 round-to-nearest-even (finite values; no NaN path needed here)
__device__ __forceinline__ u16 f2bf(float f) {
  unsigned int u = __float_as_uint(f);
  return (u16)((u + 0x7fffu + ((u >> 16) & 1u)) >> 16);
}

// ---------------------------------------------------------------------------
// Restructure (round 1): mean-over-perms folded into W:
//   Wtil_i[d, g*512+f] = sum_j C_i[g,j] * W_i[d, j*512+f]
//   out = bf16(x) @ Wtil^T + bias  -> ONE uniform GEMM 2048 x 7168 x 4096.
// Round 2: GEMM upgraded from 128^2 2-phase (786 TF) to 256^2 8-phase
// (T3+T4 counted vmcnt + T5 setprio), keeping the verified 0-conflict
// chunk-rotation LDS swizzle and per-thread vmcnt discipline.
// ---------------------------------------------------------------------------

// ---------------------------------------------------------------------------
// Kernel 1: prep (one dispatch).  [unchanged from round 1 — ~25us, at roofline]
// ---------------------------------------------------------------------------
__global__ __launch_bounds__(256) void k_prep(
    const float* __restrict__ x,
    const int* p0, const int* p1, const int* p2, const int* p3,
    const int* p4, const int* p5, const int* p6,
    const float* W0, const float* W1, const float* W2, const float* W3,
    const float* W4, const float* W5, const float* W6,
    u16* __restrict__ Xb16, u16* __restrict__ Wtil) {
  __shared__ float sC[64];                 // C_i[g][j], g=0..7, j=0..7
  const int bid = blockIdx.x;
  const int t = threadIdx.x;
  if (bid < 1792) {
    const int r0 = bid << 2;               // global output row (n) base
    const int i = r0 >> 10;                // scale index 0..6 (uniform/block)
    const int scale = 8 - i;
    const int K = scale << 9;              // scale*512
    const int d0 = r0 - (i << 10);
    if (t < 64) {
      const int g = t >> 3, j = t & 7;
      float v = 0.f;
      if (j < scale) {
        const int* p = (i == 0) ? p0 : (i == 1) ? p1 : (i == 2) ? p2 :
                       (i == 3) ? p3 : (i == 4) ? p4 : (i == 5) ? p5 : p6;
        int cnt = 0;
        for (int s = 0; s < 12; ++s) cnt += (p[s * scale + j] == g) ? 1 : 0;
        v = (float)cnt * (1.0f / 12.0f);
      }
      sC[t] = v;
    }
    __syncthreads();
    const float* Wi = (i == 0) ? W0 : (i == 1) ? W1 : (i == 2) ? W2 :
                      (i == 3) ? W3 : (i == 4) ? W4 : (i == 5) ? W5 : W6;
    const int u = t & 63;                  // f-octet: f = u*8 .. u*8+7
    const int gq = t >> 6;                 // wave -> g pair {2gq, 2gq+1}
    u16* dst = Wtil + ((size_t)r0 << 12);  // r0 * 4096
    for (int r = 0; r < 4; ++r) {
      const float* wrow = Wi + (size_t)(d0 + r) * K;
      float a0[8], a1[8];
#pragma unroll
      for (int e = 0; e < 8; ++e) { a0[e] = 0.f; a1[e] = 0.f; }
      for (int j = 0; j < scale; ++j) {
        const float* wp = wrow + j * 512 + (u << 3);
        const float4 wa = *reinterpret_cast<const float4*>(wp);
        const float4 wb = *reinterpret_cast<const float4*>(wp + 4);
        const float c0 = sC[(gq << 4) + j];        // C[2gq][j]
        const float c1 = sC[(gq << 4) + 8 + j];    // C[2gq+1][j]
        a0[0] += c0 * wa.x; a0[1] += c0 * wa.y; a0[2] += c0 * wa.z; a0[3] += c0 * wa.w;
        a0[4] += c0 * wb.x; a0[5] += c0 * wb.y; a0[6] += c0 * wb.z; a0[7] += c0 * wb.w;
        a1[0] += c1 * wa.x; a1[1] += c1 * wa.y; a1[2] += c1 * wa.z; a1[3] += c1 * wa.w;
        a1[4] += c1 * wb.x; a1[5] += c1 * wb.y; a1[6] += c1 * wb.z; a1[7] += c1 * wb.w;
      }
      uint4 o0, o1;
      o0.x = (unsigned)f2bf(a0[0]) | ((unsigned)f2bf(a0[1]) << 16);
      o0.y = (unsigned)f2bf(a0[2]) | ((unsigned)f2bf(a0[3]) << 16);
      o0.z = (unsigned)f2bf(a0[4]) | ((unsigned)f2bf(a0[5]) << 16);
      o0.w = (unsigned)f2bf(a0[6]) | ((unsigned)f2bf(a0[7]) << 16);
      o1.x = (unsigned)f2bf(a1[0]) | ((unsigned)f2bf(a1[1]) << 16);
      o1.y = (unsigned)f2bf(a1[2]) | ((unsigned)f2bf(a1[3]) << 16);
      o1.z = (unsigned)f2bf(a1[4]) | ((unsigned)f2bf(a1[5]) << 16);
      o1.w = (unsigned)f2bf(a1[6]) | ((unsigned)f2bf(a1[7]) << 16);
      u16* drow = dst + ((size_t)r << 12) + (gq << 10) + (u << 3);
      *reinterpret_cast<uint4*>(drow) = o0;        // g = 2gq
      *reinterpret_cast<uint4*>(drow + 512) = o1;  // g = 2gq+1
    }
  } else {
    // x cast: 2048*4096 fp32 -> bf16
    const int tid0 = ((bid - 1792) << 8) | t;
    const float4* X4 = reinterpret_cast<const float4*>(x);
    uint4* O = reinterpret_cast<uint4*>(Xb16);
#pragma unroll 4
    for (int it = 0; it < 16; ++it) {
      const int e = tid0 + (it << 16);
      const float4 a = X4[(size_t)e * 2];
      const float4 c = X4[(size_t)e * 2 + 1];
      uint4 o;
      o.x = (unsigned)f2bf(a.x) | ((unsigned)f2bf(a.y) << 16);
      o.y = (unsigned)f2bf(a.z) | ((unsigned)f2bf(a.w) << 16);
      o.z = (unsigned)f2bf(c.x) | ((unsigned)f2bf(c.y) << 16);
      o.w = (unsigned)f2bf(c.z) | ((unsigned)f2bf(c.w) << 16);
      O[e] = o;
    }
  }
}

// ---------------------------------------------------------------------------
// Kernel 2: bf16 MFMA GEMM 2048 x 7168 x 4096, 256x256 tile, 8-phase schedule.
//   8 waves (2M x 4N), per-wave output 128x64, BK=64, LDS 128 KB (2 dbuf x
//   (A 256x64 + B 256x64) bf16). Iteration = 2 K-tiles x 4 phases.
//   Per phase: ds_read one reg subtile || stage one half-tile (2 gl_lds/thr)
//   -> s_barrier -> lgkmcnt(0) -> setprio(1) -> 16 MFMA -> setprio(0)
//   [-> vmcnt(2) at phases 4/8 only] -> s_barrier.
//   Buffer re-stage only after the barrier ending its last read (race-free);
//   counted vmcnt(2) keeps 1-5 half-tiles in flight across barriers.
//   LDS swizzle: chunk c of row r stored at slot (c+r)&7 (verified 0-conflict).
// ---------------------------------------------------------------------------
__device__ __forceinline__ void gl_lds16(const u16* g, u16* l) {
  __builtin_amdgcn_global_load_lds(
      (const __attribute__((address_space(1))) void*)g,
      (__attribute__((address_space(3))) void*)l, 16, 0, 0);
}

#define WAIT_VM2   0x0F72   // vmcnt=2,  expcnt/lgkm no-wait
#define WAIT_VM0   0x0F70   // vmcnt=0
#define WAIT_LGKM0 0xC07F   // lgkmcnt=0, vmcnt/expcnt no-wait

#define MFMA_Q(MB, NB, AV, BV)                                               \
  _Pragma("unroll")                                                          \
  for (int q_ = 0; q_ < 4; ++q_) {                                           \
    _Pragma("unroll")                                                        \
    for (int n_ = 0; n_ < 2; ++n_) {                                         \
      acc[(MB) + q_][(NB) + n_] = __builtin_amdgcn_mfma_f32_16x16x32_bf16(   \
          AV[q_][0], BV[n_][0], acc[(MB) + q_][(NB) + n_], 0, 0, 0);         \
      acc[(MB) + q_][(NB) + n_] = __builtin_amdgcn_mfma_f32_16x16x32_bf16(   \
          AV[q_][1], BV[n_][1], acc[(MB) + q_][(NB) + n_], 0, 0, 0);         \
    }                                                                        \
  }

#define RD_A4(DB, QB)                                                        \
  _Pragma("unroll")                                                          \
  for (int q_ = 0; q_ < 4; ++q_) {                                           \
    aR[q_][0] = *reinterpret_cast<const bf16x8*>(lds + (DB) + offA[(QB) + q_]);         \
    aR[q_][1] = *reinterpret_cast<const bf16x8*>(lds + (DB) + (offA[(QB) + q_] ^ 32));  \
  }

#define RD_B2(DB, ARR, FB)                                                   \
  _Pragma("unroll")                                                          \
  for (int n_ = 0; n_ < 2; ++n_) {                                           \
    ARR[n_][0] = *reinterpret_cast<const bf16x8*>(lds + (DB) + offB[(FB) + n_]);        \
    ARR[n_][1] = *reinterpret_cast<const bf16x8*>(lds + (DB) + (offB[(FB) + n_] ^ 32)); \
  }

__global__ __launch_bounds__(512, 2) void k_gemm(
    const u16* __restrict__ A, const u16* __restrict__ Bm,
    const float* b0, const float* b1, const float* b2, const float* b3,
    const float* b4, const float* b5, const float* b6,
    float* __restrict__ out) {
  __shared__ u16 lds[65536];          // 128 KB: dbuf d at d*32768; A at +0 (2
                                      // halves of 8192), B at +16384.
  const int bid = blockIdx.x;         // 224 = 8 m-tiles x 28 n-tiles
  const int blockM = (bid & 7) * 256;   // bid%8 = XCD: 28 blocks/XCD share A-panel
  const int blockN = (bid >> 3) * 256;

  const int tid = threadIdx.x;        // 512 threads, 8 waves
  const int lane = tid & 63;
  const int wid = tid >> 6;
  const int wr = wid >> 2;            // 0..1 -> M offset wr*128
  const int wc = wid & 3;             // 0..3 -> N offset wc*64
  const int quad = lane >> 4;
  const int l15 = lane & 15;

  // ---- staging addresses (per thread: 2 chunks per half-tile) ----
  const int srow = tid >> 3;          // 0..63
  const int sslot = tid & 7;
  const int gch = (sslot - srow) & 7; // rotation swizzle (source side)
  const u16* gA0 = A + (size_t)(blockM + srow) * 4096 + gch * 8;
  const u16* gB0 = Bm + (size_t)(blockN + srow) * 4096 + gch * 8;

  // ---- LDS read offsets (u16 units, dbuf 0, tt=0; tt=1 = off^32) ----
  int offA[8], offB[4];
#pragma unroll
  for (int q = 0; q < 8; ++q) {
    const int r = q * 16 + l15;                    // row within 128-row half
    offA[q] = wr * 8192 + r * 64 + ((quad + r) & 7) * 8;
  }
#pragma unroll
  for (int f = 0; f < 4; ++f) {
    const int r = (wc & 1) * 64 + f * 16 + l15;    // col within 128-col half
    offB[f] = 16384 + (wc >> 1) * 8192 + r * 64 + ((quad + r) & 7) * 8;
  }

  f32x4 acc[8][4];
#pragma unroll
  for (int m = 0; m < 8; ++m)
#pragma unroll
    for (int n = 0; n < 4; ++n) {
      f32x4 z = {0.f, 0.f, 0.f, 0.f};
      acc[m][n] = z;
    }

  // stage one half-tile: mat 0=A 1=B, half h, K-tile t, dbuf base db (u16)
  auto stage = [&](int mat, int h, int t, int db) {
    const u16* g = (mat ? gB0 : gA0) + (size_t)h * (128 * 4096) + (size_t)t * 64;
    u16* l = lds + db + mat * 16384 + h * 8192 + (tid << 3);
    gl_lds16(g, l);
    gl_lds16(g + (size_t)(64 * 4096), l + 4096);
  };

  // ---- prologue: tile0 (dbuf0) fully, + A-half0 of tile1 (dbuf1) ----
  stage(0, 0, 0, 0); stage(0, 1, 0, 0); stage(1, 0, 0, 0); stage(1, 1, 0, 0);
  stage(0, 0, 1, 32768);
  __builtin_amdgcn_s_waitcnt(WAIT_VM2);   // tile0 landed; tile1-h0 in flight
  __builtin_amdgcn_s_barrier();

  bf16x8 aR[4][2], bL[2][2], bH[2][2];

  for (int j = 0; j < 32; ++j) {          // 64 K-tiles, 2 per iteration
    const int t1 = 2 * j + 1;
    const int t2 = (j < 31) ? 2 * j + 2 : 63;   // staged-but-unread when clamped
    const int t3 = (j < 31) ? 2 * j + 3 : 63;

    // ---- phase 1 (dbuf0): Q(Alo,Blo); stage A-h1 of t1 ----
    RD_A4(0, 0) RD_B2(0, bL, 0)
    stage(0, 1, t1, 32768);
    __builtin_amdgcn_s_barrier();
    __builtin_amdgcn_s_waitcnt(WAIT_LGKM0);
    __builtin_amdgcn_s_setprio(1);
    MFMA_Q(0, 0, aR, bL)
    __builtin_amdgcn_s_setprio(0);
    __builtin_amdgcn_s_barrier();

    // ---- phase 2: Q(Alo,Bhi); stage B-h0 of t1 ----
    RD_B2(0, bH, 2)
    stage(1, 0, t1, 32768);
    __builtin_amdgcn_s_barrier();
    __builtin_amdgcn_s_waitcnt(WAIT_LGKM0);
    __builtin_amdgcn_s_setprio(1);
    MFMA_Q(0, 2, aR, bH)
    __builtin_amdgcn_s_setprio(0);
    __builtin_amdgcn_s_barrier();

    // ---- phase 3: Q(Ahi,Bhi); stage B-h1 of t1 ----
    RD_A4(0, 4)
    stage(1, 1, t1, 32768);
    __builtin_amdgcn_s_barrier();
    __builtin_amdgcn_s_waitcnt(WAIT_LGKM0);
    __builtin_amdgcn_s_setprio(1);
    MFMA_Q(4, 2, aR, bH)
    __builtin_amdgcn_s_setprio(0);
    __builtin_amdgcn_s_barrier();

    // ---- phase 4: Q(Ahi,Blo); stage A-h0 of t2 (dbuf0 free now); vmcnt ----
    stage(0, 0, t2, 0);
    __builtin_amdgcn_s_barrier();
    __builtin_amdgcn_s_setprio(1);
    MFMA_Q(4, 0, aR, bL)
    __builtin_amdgcn_s_setprio(0);
    __builtin_amdgcn_s_waitcnt(WAIT_VM2);   // t1 fully landed (oldest 8 of 10)
    __builtin_amdgcn_s_barrier();

    // ---- phase 5 (dbuf1): Q(Alo,Blo); stage A-h1 of t2 ----
    RD_A4(32768, 0) RD_B2(32768, bL, 0)
    stage(0, 1, t2, 0);
    __builtin_amdgcn_s_barrier();
    __builtin_amdgcn_s_waitcnt(WAIT_LGKM0);
    __builtin_amdgcn_s_setprio(1);
    MFMA_Q(0, 0, aR, bL)
    __builtin_amdgcn_s_setprio(0);
    __builtin_amdgcn_s_barrier();

    // ---- phase 6: Q(Alo,Bhi); stage B-h0 of t2 ----
    RD_B2(32768, bH, 2)
    stage(1, 0, t2, 0);
    __builtin_amdgcn_s_barrier();
    __builtin_amdgcn_s_waitcnt(WAIT_LGKM0);
    __builtin_amdgcn_s_setprio(1);
    MFMA_Q(0, 2, aR, bH)
    __builtin_amdgcn_s_setprio(0);
    __builtin_amdgcn_s_barrier();

    // ---- phase 7: Q(Ahi,Bhi); stage B-h1 of t2 ----
    RD_A4(32768, 4)
    stage(1, 1, t2, 0);
    __builtin_amdgcn_s_barrier();
    __builtin_amdgcn_s_waitcnt(WAIT_LGKM0);
    __builtin_amdgcn_s_setprio(1);
    MFMA_Q(4, 2, aR, bH)
    __builtin_amdgcn_s_setprio(0);
    __builtin_amdgcn_s_barrier();

    // ---- phase 8: Q(Ahi,Blo); stage A-h0 of t3 (dbuf1 free now); vmcnt ----
    stage(0, 0, t3, 32768);
    __builtin_amdgcn_s_barrier();
    __builtin_amdgcn_s_setprio(1);
    MFMA_Q(4, 0, aR, bL)
    __builtin_amdgcn_s_setprio(0);
    __builtin_amdgcn_s_waitcnt(WAIT_VM2);   // t2 fully landed before next ph1
    __builtin_amdgcn_s_barrier();
  }
  __builtin_amdgcn_s_waitcnt(WAIT_VM0);     // retire trailing staged loads

  // ---- epilogue: D row = 16*mq + quad*4 + reg, col = 16*nf + l15 ----
  const int isc = blockN >> 10;
  const float* bi = (isc == 0) ? b0 : (isc == 1) ? b1 : (isc == 2) ? b2 :
                    (isc == 3) ? b3 : (isc == 4) ? b4 : (isc == 5) ? b5 : b6;
#pragma unroll
  for (int nf = 0; nf < 4; ++nf) {
    const int ncol = blockN + wc * 64 + nf * 16 + l15;
    const float bias = bi[ncol & 1023];
#pragma unroll
    for (int mq = 0; mq < 8; ++mq) {
      const int mbase = blockM + wr * 128 + mq * 16 + quad * 4;
#pragma unroll
      for (int reg = 0; reg < 4; ++reg)
        out[(size_t)(mbase + reg) * 7168 + ncol] = acc[mq][nf][reg] + bias;
    }
  }
}

// ---------------------------------------------------------------------------
extern "C" void kernel_launch(void* const* d_in, const int* in_sizes, int n_in,
                              void* d_out, int out_size, void* d_ws, size_t ws_size,
                              hipStream_t stream) {
  const float* input = (const float*)d_in[0];
  const int* perms[7];
  const float* W[7];
  const float* bias[7];
  for (int i = 0; i < 7; ++i) {
    perms[i] = (const int*)d_in[1 + 3 * i];
    W[i]     = (const float*)d_in[2 + 3 * i];
    bias[i]  = (const float*)d_in[3 + 3 * i];
  }
  char* ws = (char*)d_ws;
  u16* Xb16 = (u16*)ws;                                // 2048*4096 bf16 = 16.8 MB
  u16* Wtil = (u16*)(ws + (size_t)2048 * 4096 * 2);    // 7168*4096 bf16 = 58.7 MB

  k_prep<<<2048, 256, 0, stream>>>(input,
                                   perms[0], perms[1], perms[2], perms[3],
                                   perms[4], perms[5], perms[6],
                                   W[0], W[1], W[2], W[3], W[4], W[5], W[6],
                                   Xb16, Wtil);
  k_gemm<<<224, 512, 0, stream>>>(Xb16, Wtil,
                                  bias[0], bias[1], bias[2], bias[3],
                                  bias[4], bias[5], bias[6],
                                  (float*)d_out);
}

// Round 4
// 298.151 us; speedup vs baseline: 1.0923x; 1.0177x over previous
//
#include <hip/hip_runtime.h>

typedef unsigned short u16;
typedef __bf16 bf16x8 __attribute__((ext_vector_type(8)));
typedef float f32x4 __attribute__((ext_vector_type(4)));

// fp32 -> bf16 round-to-nearest-even (finite values; no NaN path needed here)
__device__ __forceinline__ u16 f2bf(float f) {
  unsigned int u = __float_as_uint(f);
  return (u16)((u + 0x7fffu + ((u >> 16) & 1u)) >> 16);
}

// ---------------------------------------------------------------------------
// out = bf16(x) @ Wtil^T + bias, ONE uniform GEMM 2048 x 7168 x 4096, where
// Wtil folds the mean-over-perms: Wtil_i[d,g*512+f] = sum_j C_i[g,j]*W_i[d,j*512+f].
// Round 4 = round 3 hardened: global-quadrant 8-phase schedule (all 8 waves
// compute one C quadrant per phase; LDS halves free progressively; tile t+2
// staged into freed slots 5-7 phases before first read; uniform counted
// vmcnt(10)), with the final iteration PEELED into an explicit drain epilogue
// (waits step 10->8->4->2->0) instead of clamped duplicate staging.
// ---------------------------------------------------------------------------

// ---------------------------------------------------------------------------
// Kernel 1: prep (one dispatch).  [unchanged — ~25-30us, near roofline]
// ---------------------------------------------------------------------------
__global__ __launch_bounds__(256) void k_prep(
    const float* __restrict__ x,
    const int* p0, const int* p1, const int* p2, const int* p3,
    const int* p4, const int* p5, const int* p6,
    const float* W0, const float* W1, const float* W2, const float* W3,
    const float* W4, const float* W5, const float* W6,
    u16* __restrict__ Xb16, u16* __restrict__ Wtil) {
  __shared__ float sC[64];                 // C_i[g][j], g=0..7, j=0..7
  const int bid = blockIdx.x;
  const int t = threadIdx.x;
  if (bid < 1792) {
    const int r0 = bid << 2;               // global output row (n) base
    const int i = r0 >> 10;                // scale index 0..6 (uniform/block)
    const int scale = 8 - i;
    const int K = scale << 9;              // scale*512
    const int d0 = r0 - (i << 10);
    if (t < 64) {
      const int g = t >> 3, j = t & 7;
      float v = 0.f;
      if (j < scale) {
        const int* p = (i == 0) ? p0 : (i == 1) ? p1 : (i == 2) ? p2 :
                       (i == 3) ? p3 : (i == 4) ? p4 : (i == 5) ? p5 : p6;
        int cnt = 0;
        for (int s = 0; s < 12; ++s) cnt += (p[s * scale + j] == g) ? 1 : 0;
        v = (float)cnt * (1.0f / 12.0f);
      }
      sC[t] = v;
    }
    __syncthreads();
    const float* Wi = (i == 0) ? W0 : (i == 1) ? W1 : (i == 2) ? W2 :
                      (i == 3) ? W3 : (i == 4) ? W4 : (i == 5) ? W5 : W6;
    const int u = t & 63;                  // f-octet: f = u*8 .. u*8+7
    const int gq = t >> 6;                 // wave -> g pair {2gq, 2gq+1}
    u16* dst = Wtil + ((size_t)r0 << 12);  // r0 * 4096
    for (int r = 0; r < 4; ++r) {
      const float* wrow = Wi + (size_t)(d0 + r) * K;
      float a0[8], a1[8];
#pragma unroll
      for (int e = 0; e < 8; ++e) { a0[e] = 0.f; a1[e] = 0.f; }
      for (int j = 0; j < scale; ++j) {
        const float* wp = wrow + j * 512 + (u << 3);
        const float4 wa = *reinterpret_cast<const float4*>(wp);
        const float4 wb = *reinterpret_cast<const float4*>(wp + 4);
        const float c0 = sC[(gq << 4) + j];        // C[2gq][j]
        const float c1 = sC[(gq << 4) + 8 + j];    // C[2gq+1][j]
        a0[0] += c0 * wa.x; a0[1] += c0 * wa.y; a0[2] += c0 * wa.z; a0[3] += c0 * wa.w;
        a0[4] += c0 * wb.x; a0[5] += c0 * wb.y; a0[6] += c0 * wb.z; a0[7] += c0 * wb.w;
        a1[0] += c1 * wa.x; a1[1] += c1 * wa.y; a1[2] += c1 * wa.z; a1[3] += c1 * wa.w;
        a1[4] += c1 * wb.x; a1[5] += c1 * wb.y; a1[6] += c1 * wb.z; a1[7] += c1 * wb.w;
      }
      uint4 o0, o1;
      o0.x = (unsigned)f2bf(a0[0]) | ((unsigned)f2bf(a0[1]) << 16);
      o0.y = (unsigned)f2bf(a0[2]) | ((unsigned)f2bf(a0[3]) << 16);
      o0.z = (unsigned)f2bf(a0[4]) | ((unsigned)f2bf(a0[5]) << 16);
      o0.w = (unsigned)f2bf(a0[6]) | ((unsigned)f2bf(a0[7]) << 16);
      o1.x = (unsigned)f2bf(a1[0]) | ((unsigned)f2bf(a1[1]) << 16);
      o1.y = (unsigned)f2bf(a1[2]) | ((unsigned)f2bf(a1[3]) << 16);
      o1.z = (unsigned)f2bf(a1[4]) | ((unsigned)f2bf(a1[5]) << 16);
      o1.w = (unsigned)f2bf(a1[6]) | ((unsigned)f2bf(a1[7]) << 16);
      u16* drow = dst + ((size_t)r << 12) + (gq << 10) + (u << 3);
      *reinterpret_cast<uint4*>(drow) = o0;        // g = 2gq
      *reinterpret_cast<uint4*>(drow + 512) = o1;  // g = 2gq+1
    }
  } else {
    // x cast: 2048*4096 fp32 -> bf16
    const int tid0 = ((bid - 1792) << 8) | t;
    const float4* X4 = reinterpret_cast<const float4*>(x);
    uint4* O = reinterpret_cast<uint4*>(Xb16);
#pragma unroll 4
    for (int it = 0; it < 16; ++it) {
      const int e = tid0 + (it << 16);
      const float4 a = X4[(size_t)e * 2];
      const float4 c = X4[(size_t)e * 2 + 1];
      uint4 o;
      o.x = (unsigned)f2bf(a.x) | ((unsigned)f2bf(a.y) << 16);
      o.y = (unsigned)f2bf(a.z) | ((unsigned)f2bf(a.w) << 16);
      o.z = (unsigned)f2bf(c.x) | ((unsigned)f2bf(c.y) << 16);
      o.w = (unsigned)f2bf(c.z) | ((unsigned)f2bf(c.w) << 16);
      O[e] = o;
    }
  }
}

// ---------------------------------------------------------------------------
// Kernel 2: bf16 MFMA GEMM 2048 x 7168 x 4096, 256x256 tile, 8 waves,
// global-quadrant 8-phase schedule.
//   LDS 128 KB: dbuf d at d*32768 u16; A at +0 (lo half rows 0-127 at +0,
//   hi at +8192), B at +16384 (lo cols at +0, hi at +8192).
//   Phase p computes quadrant Qp of the 256x256 C for K-tile t:
//     Q1=(Mlo,Nlo) Q2=(Mlo,Nhi) Q3=(Mhi,Nhi) Q4=(Mhi,Nlo)
//   8 waves split a 128x128 quadrant 2x4 -> per-wave 64x32 per quadrant.
//   Register reuse: aR(A-lo) ph1-2, aR(A-hi) ph3-4, bL ph1&4, bH ph2-3.
//   Staging (1 half-tile = 2 gl_lds/thread per phase, into the slot freed the
//   previous phase, tile t+2): ph1:Ahi(t+1) ph2:Alo(t+2) ph3:Blo(t+2)
//   ph4:Bhi(t+2) ph5:Ahi(t+2) ph6:Alo(t+3) ph7:Blo(t+3) ph8:Bhi(t+3).
//   vmcnt(10) before end-barrier of phases 1,2,4,5,6,8: every waited-on load
//   was issued 5 phases (~1200+ cyc) earlier -> HBM latency hidden.
//   LDS swizzle: chunk c of row r at slot (c+r)&7 (verified 0-conflict).
//   Final iteration peeled: drain epilogue, waits 10->8->4->2->0.
// ---------------------------------------------------------------------------
__device__ __forceinline__ void gl_lds16(const u16* g, u16* l) {
  __builtin_amdgcn_global_load_lds(
      (const __attribute__((address_space(1))) void*)g,
      (__attribute__((address_space(3))) void*)l, 16, 0, 0);
}

#define WAIT_VM10  0x0F7A   // vmcnt=10, expcnt=7(nowait), lgkmcnt=15(nowait)
#define WAIT_VM8   0x0F78
#define WAIT_VM4   0x0F74
#define WAIT_VM2   0x0F72
#define WAIT_VM0   0x0F70
#define WAIT_LGKM0 0xC07F   // lgkmcnt=0, vmcnt=63(nowait), expcnt=7

#define MFMA_Q(QD, AV, BV)                                                   \
  _Pragma("unroll")                                                          \
  for (int mf_ = 0; mf_ < 4; ++mf_) {                                        \
    _Pragma("unroll")                                                        \
    for (int nf_ = 0; nf_ < 2; ++nf_) {                                      \
      acc[QD][mf_][nf_] = __builtin_amdgcn_mfma_f32_16x16x32_bf16(           \
          AV[mf_][0], BV[nf_][0], acc[QD][mf_][nf_], 0, 0, 0);               \
      acc[QD][mf_][nf_] = __builtin_amdgcn_mfma_f32_16x16x32_bf16(           \
          AV[mf_][1], BV[nf_][1], acc[QD][mf_][nf_], 0, 0, 0);               \
    }                                                                        \
  }

#define RD_A(BASE)                                                           \
  _Pragma("unroll")                                                          \
  for (int mf_ = 0; mf_ < 4; ++mf_) {                                        \
    aR[mf_][0] = *reinterpret_cast<const bf16x8*>(lds + (BASE) + offA[mf_]);        \
    aR[mf_][1] = *reinterpret_cast<const bf16x8*>(lds + (BASE) + (offA[mf_] ^ 32)); \
  }

#define RD_B(BASE, ARR)                                                      \
  _Pragma("unroll")                                                          \
  for (int nf_ = 0; nf_ < 2; ++nf_) {                                        \
    ARR[nf_][0] = *reinterpret_cast<const bf16x8*>(lds + (BASE) + offB[nf_]);        \
    ARR[nf_][1] = *reinterpret_cast<const bf16x8*>(lds + (BASE) + (offB[nf_] ^ 32)); \
  }

#define PH_BAR  __builtin_amdgcn_s_barrier()
#define PH_LGKM __builtin_amdgcn_s_waitcnt(WAIT_LGKM0)
#define PRIO1   __builtin_amdgcn_s_setprio(1)
#define PRIO0   __builtin_amdgcn_s_setprio(0)

__global__ __launch_bounds__(512, 2) void k_gemm(
    const u16* __restrict__ A, const u16* __restrict__ Bm,
    const float* b0, const float* b1, const float* b2, const float* b3,
    const float* b4, const float* b5, const float* b6,
    float* __restrict__ out) {
  __shared__ u16 lds[65536];          // 128 KB
  const int bid = blockIdx.x;         // 224 = 8 m-tiles x 28 n-tiles
  const int blockM = (bid & 7) * 256;   // bid%8 = XCD: 28 blocks/XCD share A-panel
  const int blockN = (bid >> 3) * 256;

  const int tid = threadIdx.x;        // 512 threads, 8 waves
  const int lane = tid & 63;
  const int wid = tid >> 6;
  const int wm = (wid >> 2) * 64;     // row offset within 128-row quadrant
  const int wn = (wid & 3) * 32;      // col offset within 128-col quadrant
  const int quad = lane >> 4;
  const int l15 = lane & 15;

  // ---- staging addresses (2 chunks per half-tile per thread) ----
  const int srow = tid >> 3;          // 0..63
  const int sslot = tid & 7;
  const int gch = (sslot - srow) & 7; // rotation swizzle (source side)
  const u16* gA0 = A + (size_t)(blockM + srow) * 4096 + gch * 8;
  const u16* gB0 = Bm + (size_t)(blockN + srow) * 4096 + gch * 8;

  // ---- within-half LDS read offsets (u16 units; hi half = +8192) ----
  int offA[4], offB[2];
#pragma unroll
  for (int mf = 0; mf < 4; ++mf) {
    const int r = wm + mf * 16 + l15;              // 0..127
    offA[mf] = r * 64 + ((quad + r) & 7) * 8;
  }
#pragma unroll
  for (int nf = 0; nf < 2; ++nf) {
    const int r = wn + nf * 16 + l15;              // 0..127
    offB[nf] = 16384 + r * 64 + ((quad + r) & 7) * 8;
  }

  f32x4 acc[4][4][2];
#pragma unroll
  for (int q = 0; q < 4; ++q)
#pragma unroll
    for (int m = 0; m < 4; ++m)
#pragma unroll
      for (int n = 0; n < 2; ++n) {
        f32x4 z = {0.f, 0.f, 0.f, 0.f};
        acc[q][m][n] = z;
      }

  // stage one half-tile: mat 0=A 1=B, half h, K-tile t, dbuf base db (u16)
  auto stage = [&](int mat, int h, int t, int db) {
    const u16* g = (mat ? gB0 : gA0) + (size_t)h * (128 * 4096) + (size_t)t * 64;
    u16* l = lds + db + mat * 16384 + h * 8192 + (tid << 3);
    gl_lds16(g, l);
    gl_lds16(g + (size_t)(64 * 4096), l + 4096);
  };

  // ---- prologue: t0 fully (Alo,Blo,Bhi,Ahi) -> db0; t1 Alo,Blo,Bhi -> db1.
  // (t1's Ahi is staged by ph1 of iteration 0.)  14 loads in flight;
  // vmcnt(10) => t0's Alo+Blo landed before ph1 reads them.
  stage(0, 0, 0, 0); stage(1, 0, 0, 0); stage(1, 1, 0, 0); stage(0, 1, 0, 0);
  stage(0, 0, 1, 32768); stage(1, 0, 1, 32768); stage(1, 1, 1, 32768);
  __builtin_amdgcn_s_waitcnt(WAIT_VM10);
  PH_BAR;

  bf16x8 aR[4][2], bL[2][2], bH[2][2];

  for (int j = 0; j < 31; ++j) {          // tiles 0..61; prefetch through 63
    const int t1 = 2 * j + 1;
    const int t2 = 2 * j + 2;
    const int t3 = 2 * j + 3;

    // ---- ph1 (db0): Q1=(Mlo,Nlo); stage Ahi(t1)->db1 ----
    RD_A(0) RD_B(0, bL)
    stage(0, 1, t1, 32768);
    PH_BAR; PH_LGKM; PRIO1; MFMA_Q(0, aR, bL) PRIO0;
    __builtin_amdgcn_s_waitcnt(WAIT_VM10); PH_BAR;

    // ---- ph2: Q2=(Mlo,Nhi); stage Alo(t2)->db0 (slot freed ph1) ----
    RD_B(8192, bH)
    stage(0, 0, t2, 0);
    PH_BAR; PH_LGKM; PRIO1; MFMA_Q(1, aR, bH) PRIO0;
    __builtin_amdgcn_s_waitcnt(WAIT_VM10); PH_BAR;

    // ---- ph3: Q3=(Mhi,Nhi); stage Blo(t2)->db0 (freed ph1) ----
    RD_A(8192)
    stage(1, 0, t2, 0);
    PH_BAR; PH_LGKM; PRIO1; MFMA_Q(2, aR, bH) PRIO0;
    PH_BAR;

    // ---- ph4: Q4=(Mhi,Nlo) [regs only]; stage Bhi(t2)->db0 (freed ph2) ----
    stage(1, 1, t2, 0);
    PH_BAR; PRIO1; MFMA_Q(3, aR, bL) PRIO0;
    __builtin_amdgcn_s_waitcnt(WAIT_VM10); PH_BAR;

    // ---- ph5 (db1): Q1; stage Ahi(t2)->db0 (freed ph3) ----
    RD_A(32768) RD_B(32768, bL)
    stage(0, 1, t2, 0);
    PH_BAR; PH_LGKM; PRIO1; MFMA_Q(0, aR, bL) PRIO0;
    __builtin_amdgcn_s_waitcnt(WAIT_VM10); PH_BAR;

    // ---- ph6: Q2; stage Alo(t3)->db1 (freed ph5) ----
    RD_B(32768 + 8192, bH)
    stage(0, 0, t3, 32768);
    PH_BAR; PH_LGKM; PRIO1; MFMA_Q(1, aR, bH) PRIO0;
    __builtin_amdgcn_s_waitcnt(WAIT_VM10); PH_BAR;

    // ---- ph7: Q3; stage Blo(t3)->db1 (freed ph5) ----
    RD_A(32768 + 8192)
    stage(1, 0, t3, 32768);
    PH_BAR; PH_LGKM; PRIO1; MFMA_Q(2, aR, bH) PRIO0;
    PH_BAR;

    // ---- ph8: Q4 [regs only]; stage Bhi(t3)->db1 (freed ph6) ----
    stage(1, 1, t3, 32768);
    PH_BAR; PRIO1; MFMA_Q(3, aR, bL) PRIO0;
    __builtin_amdgcn_s_waitcnt(WAIT_VM10); PH_BAR;
  }

  // ---- drain epilogue: tiles 62 (db0) and 63 (db1). Only one stage left
  // (Ahi(63)); counted waits step down exactly with the load queue:
  // entry outstanding (oldest->newest): Bhi62,Ahi62,Alo63,Blo63,Bhi63 (10).
  {
    // ph1: Q1 of tile 62; stage Ahi(63)->db1 (+2 -> 12)
    RD_A(0) RD_B(0, bL)
    stage(0, 1, 63, 32768);
    PH_BAR; PH_LGKM; PRIO1; MFMA_Q(0, aR, bL) PRIO0;
    __builtin_amdgcn_s_waitcnt(WAIT_VM10); PH_BAR;   // Bhi62 landed

    // ph2: Q2 of 62
    RD_B(8192, bH)
    PH_BAR; PH_LGKM; PRIO1; MFMA_Q(1, aR, bH) PRIO0;
    __builtin_amdgcn_s_waitcnt(WAIT_VM8); PH_BAR;    // Ahi62 landed

    // ph3: Q3 of 62
    RD_A(8192)
    PH_BAR; PH_LGKM; PRIO1; MFMA_Q(2, aR, bH) PRIO0;
    PH_BAR;

    // ph4: Q4 of 62 [regs only]
    PH_BAR; PRIO1; MFMA_Q(3, aR, bL) PRIO0;
    __builtin_amdgcn_s_waitcnt(WAIT_VM4); PH_BAR;    // Alo63+Blo63 landed

    // ph5: Q1 of tile 63 (db1)
    RD_A(32768) RD_B(32768, bL)
    PH_BAR; PH_LGKM; PRIO1; MFMA_Q(0, aR, bL) PRIO0;
    __builtin_amdgcn_s_waitcnt(WAIT_VM2); PH_BAR;    // Bhi63 landed

    // ph6: Q2 of 63
    RD_B(32768 + 8192, bH)
    PH_BAR; PH_LGKM; PRIO1; MFMA_Q(1, aR, bH) PRIO0;
    __builtin_amdgcn_s_waitcnt(WAIT_VM0); PH_BAR;    // Ahi63 landed (drained)

    // ph7: Q3 of 63
    RD_A(32768 + 8192)
    PH_BAR; PH_LGKM; PRIO1; MFMA_Q(2, aR, bH) PRIO0;
    PH_BAR;

    // ph8: Q4 of 63 [regs only]
    PRIO1; MFMA_Q(3, aR, bL) PRIO0;
  }

  // ---- epilogue: D row = 16*mf + quad*4 + reg (in quadrant), col = 16*nf + l15
  const int isc = blockN >> 10;
  const float* bi = (isc == 0) ? b0 : (isc == 1) ? b1 : (isc == 2) ? b2 :
                    (isc == 3) ? b3 : (isc == 4) ? b4 : (isc == 5) ? b5 : b6;
#pragma unroll
  for (int qd = 0; qd < 4; ++qd) {
    const int Mq = (qd >= 2) ? 128 : 0;
    const int Nq = (qd == 1 || qd == 2) ? 128 : 0;
#pragma unroll
    for (int nf = 0; nf < 2; ++nf) {
      const int ncol = blockN + Nq + wn + nf * 16 + l15;
      const float bias = bi[ncol & 1023];
#pragma unroll
      for (int mf = 0; mf < 4; ++mf) {
        const int mbase = blockM + Mq + wm + mf * 16 + quad * 4;
#pragma unroll
        for (int reg = 0; reg < 4; ++reg)
          out[(size_t)(mbase + reg) * 7168 + ncol] = acc[qd][mf][nf][reg] + bias;
      }
    }
  }
}

// ---------------------------------------------------------------------------
extern "C" void kernel_launch(void* const* d_in, const int* in_sizes, int n_in,
                              void* d_out, int out_size, void* d_ws, size_t ws_size,
                              hipStream_t stream) {
  const float* input = (const float*)d_in[0];
  const int* perms[7];
  const float* W[7];
  const float* bias[7];
  for (int i = 0; i < 7; ++i) {
    perms[i] = (const int*)d_in[1 + 3 * i];
    W[i]     = (const float*)d_in[2 + 3 * i];
    bias[i]  = (const float*)d_in[3 + 3 * i];
  }
  char* ws = (char*)d_ws;
  u16* Xb16 = (u16*)ws;                                // 2048*4096 bf16 = 16.8 MB
  u16* Wtil = (u16*)(ws + (size_t)2048 * 4096 * 2);    // 7168*4096 bf16 = 58.7 MB

  k_prep<<<2048, 256, 0, stream>>>(input,
                                   perms[0], perms[1], perms[2], perms[3],
                                   perms[4], perms[5], perms[6],
                                   W[0], W[1], W[2], W[3], W[4], W[5], W[6],
                                   Xb16, Wtil);
  k_gemm<<<224, 512, 0, stream>>>(Xb16, Wtil,
                                  bias[0], bias[1], bias[2], bias[3],
                                  bias[4], bias[5], bias[6],
                                  (float*)d_out);
}